// Round 21
// baseline (76.628 us; speedup 1.0000x reference)
//
#include <hip/hip_runtime.h>
#include <math.h>

// Problem constants (from reference)
#define N_Q 4096
#define M_K 8192
#define D_DIM 512
#define P_IDX 4
#define INV_TEMP 10.0f

#define NCHUNK 64           // 8192 cols / 128-col (interleaved) merged chunks

typedef __attribute__((ext_vector_type(8))) _Float16 f16x8;
typedef __attribute__((ext_vector_type(16))) float f32x16;

// ---------------------------------------------------------------------------
// Pack fp32 row-major [nrows][512] into MFMA-fragment-ordered fp16 (Q and K
// fused in one launch; Q pre-scaled by INV_TEMP).
// 16B chunk index c = (rb*32+ks)*64 + hi*32 + lx holds row rb*32+lx,
// k = (ks*2+hi)*8 .. +8.  A wave's 32x32x16 fragment for (rb, ks) is the
// contiguous 1 KB at chunk (rb*32+ks)*64 + lane -> perfectly coalesced.
// ---------------------------------------------------------------------------
__global__ __launch_bounds__(256)
void pack_f16(const float* __restrict__ Q, const float* __restrict__ K,
              _Float16* __restrict__ Pq, _Float16* __restrict__ Pk,
              int qunits, int totunits)
{
    const int wunit = blockIdx.x * 4 + (threadIdx.x >> 6);
    if (wunit >= totunits) return;
    const bool isq = (wunit < qunits);
    const int u = isq ? wunit : wunit - qunits;
    const float* X = isq ? Q : K;
    _Float16* P = isq ? Pq : Pk;
    const float scale = isq ? INV_TEMP : 1.0f;
    const int rb = u >> 5, ks = u & 31;
    const int lane = threadIdx.x & 63;
    const int hi = lane >> 5, lx = lane & 31;
    const int row = rb * 32 + lx;
    const float4* src = (const float4*)(X + (size_t)row * D_DIM + ks * 16 + hi * 8);
    float4 v0 = src[0], v1 = src[1];
    f16x8 o;
    o[0] = (_Float16)(v0.x * scale); o[1] = (_Float16)(v0.y * scale);
    o[2] = (_Float16)(v0.z * scale); o[3] = (_Float16)(v0.w * scale);
    o[4] = (_Float16)(v1.x * scale); o[5] = (_Float16)(v1.y * scale);
    o[6] = (_Float16)(v1.z * scale); o[7] = (_Float16)(v1.w * scale);
    ((f16x8*)P)[(size_t)u * 64 + lane] = o;
}

// ---------------------------------------------------------------------------
// LDS-free, barrier-free swapped fp16 MFMA GEMM: scores^T = MFMA(K, Q).
// Depth-4 rotating pipeline (R15-verified optimum): 4 fragment sets R/S/T/U
// in flight; set s consumed at step ks, reloaded for ks+4; no copies,
// counted vmcnt by compiler; setprio around MFMA quartets.
// Epilogue: in-lane {mask,max,argmax,sumexp} -> shfl_xor(32) hi-merge
// (R18-verified) -> cross-wr merge via 2 KB LDS + one barrier -> one
// 128-col chunk partial per qrow per block (NCHUNK=64, part = 4 MB).
// 128(K) x 128(Q) tile, 4 waves (2 wr x 2 wc), acc[2][2] f32x16.
// Grid (64 kTiles, 32 qTiles), block 256.
// ---------------------------------------------------------------------------
#define MFMA_QUARTET(A0, A1, B0, B1)                                            \
    __builtin_amdgcn_s_setprio(1);                                              \
    acc[0][0] = __builtin_amdgcn_mfma_f32_32x32x16_f16(A0, B0, acc[0][0], 0, 0, 0); \
    acc[0][1] = __builtin_amdgcn_mfma_f32_32x32x16_f16(A0, B1, acc[0][1], 0, 0, 0); \
    acc[1][0] = __builtin_amdgcn_mfma_f32_32x32x16_f16(A1, B0, acc[1][0], 0, 0, 0); \
    acc[1][1] = __builtin_amdgcn_mfma_f32_32x32x16_f16(A1, B1, acc[1][1], 0, 0, 0); \
    __builtin_amdgcn_s_setprio(0);

__global__ __launch_bounds__(256)
void scores_mfma(const _Float16* __restrict__ Qp, const _Float16* __restrict__ Kp,
                 const int* __restrict__ ign, float4* __restrict__ part)
{
    __shared__ float4 mrg[2][2][32];      // [wc][j][lx] partials from wr=0

    const int tid = threadIdx.x;          // 0..255
    const int lane = tid & 63;
    const int wave = tid >> 6;            // 0..3
    const int wr = wave >> 1, wc = wave & 1;
    const int hi = lane >> 5, lx = lane & 31;
    const int bx = blockIdx.x;            // K-tile (128 rows), 0..63
    const int by = blockIdx.y;            // Q-tile (128 rows), 0..31

    const f16x8* Kp8 = (const f16x8*)Kp;
    const f16x8* Qp8 = (const f16x8*)Qp;
    const f16x8* A0p = Kp8 + ((size_t)(bx * 4 + wr * 2 + 0) * 32) * 64 + lane;
    const f16x8* A1p = Kp8 + ((size_t)(bx * 4 + wr * 2 + 1) * 32) * 64 + lane;
    const f16x8* B0p = Qp8 + ((size_t)(by * 4 + wc * 2 + 0) * 32) * 64 + lane;
    const f16x8* B1p = Qp8 + ((size_t)(by * 4 + wc * 2 + 1) * 32) * 64 + lane;

    f32x16 acc[2][2];
#pragma unroll
    for (int i = 0; i < 2; ++i)
#pragma unroll
        for (int j = 0; j < 2; ++j) acc[i][j] = (f32x16)0.f;

    // prologue: sets for ks = 0 (R), 1 (S), 2 (T), 3 (U)
    f16x8 rA0 = A0p[0],   rA1 = A1p[0],   rB0 = B0p[0],   rB1 = B1p[0];
    f16x8 sA0 = A0p[64],  sA1 = A1p[64],  sB0 = B0p[64],  sB1 = B1p[64];
    f16x8 tA0 = A0p[128], tA1 = A1p[128], tB0 = B0p[128], tB1 = B1p[128];
    f16x8 uA0 = A0p[192], uA1 = A1p[192], uB0 = B0p[192], uB1 = B1p[192];

    for (int ks = 0; ks < 32; ks += 4) {
        MFMA_QUARTET(rA0, rA1, rB0, rB1)
        if (ks + 4 < 32) {
            const int o = (ks + 4) * 64;
            rA0 = A0p[o]; rA1 = A1p[o]; rB0 = B0p[o]; rB1 = B1p[o];
        }
        MFMA_QUARTET(sA0, sA1, sB0, sB1)
        if (ks + 5 < 32) {
            const int o = (ks + 5) * 64;
            sA0 = A0p[o]; sA1 = A1p[o]; sB0 = B0p[o]; sB1 = B1p[o];
        }
        MFMA_QUARTET(tA0, tA1, tB0, tB1)
        if (ks + 6 < 32) {
            const int o = (ks + 6) * 64;
            tA0 = A0p[o]; tA1 = A1p[o]; tB0 = B0p[o]; tB1 = B1p[o];
        }
        MFMA_QUARTET(uA0, uA1, uB0, uB1)
        if (ks + 7 < 32) {
            const int o = (ks + 7) * 64;
            uA0 = A0p[o]; uA1 = A1p[o]; uB0 = B0p[o]; uB1 = B1p[o];
        }
    }

    // Epilogue:
    //   acc[i][j][r] = score(qrow = by*128 + wc*64 + j*32 + lx,
    //                        kcol = bx*128 + wr*64 + i*32 + (r&3)+8*(r>>2)+4*hi)
    // Step 1 (in-lane + hi-merge, R18-verified): per j -> 64-col partial.
    const int kbase = bx * 128 + wr * 64 + 4 * hi;
    float bmj[2], sej[2]; int bij[2];
#pragma unroll
    for (int j = 0; j < 2; ++j) {
        const int qrow = by * 128 + wc * 64 + j * 32 + lx;
        const int4 ig = ((const int4*)ign)[qrow];   // 4 ignore indices, 16B
        float bm = -INFINITY; int bi = 0x7fffffff;
#pragma unroll
        for (int i = 0; i < 2; ++i) {
#pragma unroll
            for (int r = 0; r < 16; ++r) {
                const int col = kbase + i * 32 + (r & 3) + 8 * (r >> 2);
                float x = acc[i][j][r];
                if (col == ig.x || col == ig.y || col == ig.z || col == ig.w)
                    x = -INFINITY;
                acc[i][j][r] = x;
                if (x > bm || (x == bm && col < bi)) { bm = x; bi = col; }
            }
        }
        float se = 0.f;
#pragma unroll
        for (int i = 0; i < 2; ++i)
#pragma unroll
            for (int r = 0; r < 16; ++r)
                se += __expf(acc[i][j][r] - bm);

        // merge with partner hi-half (same qrow, other 32 k-cols)
        const float obm = __shfl_xor(bm, 32);
        const float ose = __shfl_xor(se, 32);
        const int   obi = __shfl_xor(bi, 32);
        const float nm = fmaxf(bm, obm);
        se = se * __expf(bm - nm) + ose * __expf(obm - nm);
        if (obm > bm || (obm == bm && obi < bi)) bi = obi;
        bm = nm;
        bmj[j] = bm; sej[j] = se; bij[j] = bi;
    }

    // Step 2: cross-wr merge via LDS (wr=0 posts, wr=1 merges+writes).
    if (wr == 0 && hi == 0) {
#pragma unroll
        for (int j = 0; j < 2; ++j)
            mrg[wc][j][lx] = make_float4(bmj[j], sej[j], __int_as_float(bij[j]), 0.f);
    }
    __syncthreads();
    if (wr == 1 && hi == 0) {
#pragma unroll
        for (int j = 0; j < 2; ++j) {
            const float4 o = mrg[wc][j][lx];
            const int   obi = __float_as_int(o.z);
            float bm = bmj[j], se = sej[j]; int bi = bij[j];
            const float nm = fmaxf(bm, o.x);
            se = se * __expf(bm - nm) + o.y * __expf(o.x - nm);
            if (o.x > bm || (o.x == bm && obi < bi)) bi = obi;
            bm = nm;
            const int qrow = by * 128 + wc * 64 + j * 32 + lx;
            part[(size_t)qrow * NCHUNK + bx] =
                make_float4(bm, se, __int_as_float(bi), 0.f);
        }
    }
}

// ---------------------------------------------------------------------------
// Kernel B: 4 rows per 256-thread block (one wave per row).  Merge 64
// chunk partials (one load per lane) -> lse + argmax; positives recomputed
// from the PACKED fp16 copies (Qp pre-scaled by 1/TEMP, so no extra scale):
// lane l covers k in [8l, 8l+8) of a row via chunk
//   rb*2048 + (l>>1)*64 + (l&1)*32 + (row&31).
// Positive-score fp16 noise ~0.08 post-temp -> loss error ~7 << 5.1e4
// threshold; corrects compares indices only (unaffected).
// ---------------------------------------------------------------------------
__global__ __launch_bounds__(256)
void combine_kernel(const float4* __restrict__ part,
                    const _Float16* __restrict__ Qp, const _Float16* __restrict__ Kp,
                    const int* __restrict__ pos,
                    float* __restrict__ logp, float* __restrict__ corrects)
{
    const int row = blockIdx.x * 4 + (threadIdx.x >> 6);
    const int lane = threadIdx.x & 63;

    float4 p0 = part[(size_t)row * NCHUNK + lane];
    float m = p0.x, s = p0.y, av = p0.x;
    int ai = __float_as_int(p0.z);

#pragma unroll
    for (int off = 32; off >= 1; off >>= 1) {
        float om = __shfl_xor(m, off);
        float os = __shfl_xor(s, off);
        float oav = __shfl_xor(av, off);
        int oi = __shfl_xor(ai, off);
        float nm = fmaxf(m, om);
        s = s * __expf(m - nm) + os * __expf(om - nm);
        m = nm;
        if (oav > av || (oav == av && oi < ai)) { av = oav; ai = oi; }
    }
    float lse = m + __logf(s);

    int pi[4];
#pragma unroll
    for (int p = 0; p < 4; ++p) pi[p] = pos[row * P_IDX + p];

    // positive dot-products from packed fp16 (already includes 1/TEMP on Q)
    const f16x8* Qp8 = (const f16x8*)Qp;
    const f16x8* Kp8 = (const f16x8*)Kp;
    const int koff = (lane >> 1) * 64 + (lane & 1) * 32;   // chunk offset of lane's k-octet
    f16x8 qv = Qp8[(size_t)(row >> 5) * 2048 + koff + (row & 31)];
    float d[4];
#pragma unroll
    for (int p = 0; p < 4; ++p) {
        f16x8 kv = Kp8[(size_t)(pi[p] >> 5) * 2048 + koff + (pi[p] & 31)];
        float acc = 0.f;
#pragma unroll
        for (int e = 0; e < 8; ++e)
            acc = fmaf((float)qv[e], (float)kv[e], acc);
        d[p] = acc;
    }
#pragma unroll
    for (int off = 32; off >= 1; off >>= 1) {
#pragma unroll
        for (int p = 0; p < 4; ++p) d[p] += __shfl_xor(d[p], off);
    }

    if (lane == 0) {
        // d[] already on the scores/TEMP scale (Qp pre-scaled)
        const bool v1 = (pi[1] != pi[0]);
        const bool v2 = (pi[2] != pi[0]) && (pi[2] != pi[1]);
        const bool v3 = (pi[3] != pi[0]) && (pi[3] != pi[1]) && (pi[3] != pi[2]);
        float pm = d[0];
        if (v1) pm = fmaxf(pm, d[1]);
        if (v2) pm = fmaxf(pm, d[2]);
        if (v3) pm = fmaxf(pm, d[3]);
        float pse = __expf(d[0] - pm);
        if (v1) pse += __expf(d[1] - pm);
        if (v2) pse += __expf(d[2] - pm);
        if (v3) pse += __expf(d[3] - pm);
        float pos_lse = pm + __logf(pse);
        logp[row] = pos_lse - lse;
        bool corr = (ai == pi[0]) || (ai == pi[1]) || (ai == pi[2]) || (ai == pi[3]);
        corrects[row] = corr ? 1.0f : 0.0f;
    }
}

// ---------------------------------------------------------------------------
// Kernel C: deterministic fixed-order reduction of logp -> loss
// ---------------------------------------------------------------------------
__global__ __launch_bounds__(256)
void loss_kernel(const float* __restrict__ logp, float* __restrict__ out)
{
    __shared__ float sm[256];
    const int t = threadIdx.x;
    float s = 0.f;
    for (int i = t; i < N_Q; i += 256) s += logp[i];
    sm[t] = s;
    __syncthreads();
    for (int off = 128; off >= 1; off >>= 1) {
        if (t < off) sm[t] += sm[t + off];
        __syncthreads();
    }
    if (t == 0) out[0] = -sm[0];
}

// ---------------------------------------------------------------------------
extern "C" void kernel_launch(void* const* d_in, const int* in_sizes, int n_in,
                              void* d_out, int out_size, void* d_ws, size_t ws_size,
                              hipStream_t stream)
{
    const float* Q = (const float*)d_in[0];
    const float* K = (const float*)d_in[1];
    const int* pos = (const int*)d_in[2];
    const int* ign = (const int*)d_in[3];
    float* out = (float*)d_out;

    // workspace layout (total ~16 MB)
    _Float16* Qp = (_Float16*)d_ws;                              // 4 MB
    _Float16* Kp = Qp + (size_t)N_Q * D_DIM;                     // 8 MB
    float4* part = (float4*)(Kp + (size_t)M_K * D_DIM);          // 4 MB
    float* logp = (float*)(part + (size_t)N_Q * NCHUNK);         // 16 KB

    const int qunits = N_Q / 32 * 32;     // 4096
    const int totunits = qunits + M_K / 32 * 32;   // 12288
    pack_f16<<<totunits / 4, 256, 0, stream>>>(Q, K, Qp, Kp, qunits, totunits);

    dim3 gridA(M_K / 128, N_Q / 128);   // 64 kTiles x 32 qTiles
    scores_mfma<<<gridA, 256, 0, stream>>>(Qp, Kp, ign, part);
    combine_kernel<<<N_Q / 4, 256, 0, stream>>>(part, Qp, Kp, pos, logp, out + 1);
    loss_kernel<<<1, 256, 0, stream>>>(logp, out);
}

// Round 22
// 73.338 us; speedup vs baseline: 1.0449x; 1.0449x over previous
//
#include <hip/hip_runtime.h>
#include <math.h>

// Problem constants (from reference)
#define N_Q 4096
#define M_K 8192
#define D_DIM 512
#define P_IDX 4
#define INV_TEMP 10.0f

#define NCHUNK 64           // 8192 cols / 128-col (interleaved) merged chunks

typedef __attribute__((ext_vector_type(8))) _Float16 f16x8;
typedef __attribute__((ext_vector_type(16))) float f32x16;

// ---------------------------------------------------------------------------
// Pack fp32 row-major [nrows][512] into MFMA-fragment-ordered fp16 (Q and K
// fused in one launch; Q pre-scaled by INV_TEMP).
// A wave's 32x32x16 fragment for (rb, ks) is the contiguous 1 KB at chunk
// (rb*32+ks)*64 + lane -> perfectly coalesced stream.
// ---------------------------------------------------------------------------
__global__ __launch_bounds__(256)
void pack_f16(const float* __restrict__ Q, const float* __restrict__ K,
              _Float16* __restrict__ Pq, _Float16* __restrict__ Pk,
              int qunits, int totunits)
{
    const int wunit = blockIdx.x * 4 + (threadIdx.x >> 6);
    if (wunit >= totunits) return;
    const bool isq = (wunit < qunits);
    const int u = isq ? wunit : wunit - qunits;
    const float* X = isq ? Q : K;
    _Float16* P = isq ? Pq : Pk;
    const float scale = isq ? INV_TEMP : 1.0f;
    const int rb = u >> 5, ks = u & 31;
    const int lane = threadIdx.x & 63;
    const int hi = lane >> 5, lx = lane & 31;
    const int row = rb * 32 + lx;
    const float4* src = (const float4*)(X + (size_t)row * D_DIM + ks * 16 + hi * 8);
    float4 v0 = src[0], v1 = src[1];
    f16x8 o;
    o[0] = (_Float16)(v0.x * scale); o[1] = (_Float16)(v0.y * scale);
    o[2] = (_Float16)(v0.z * scale); o[3] = (_Float16)(v0.w * scale);
    o[4] = (_Float16)(v1.x * scale); o[5] = (_Float16)(v1.y * scale);
    o[6] = (_Float16)(v1.z * scale); o[7] = (_Float16)(v1.w * scale);
    ((f16x8*)P)[(size_t)u * 64 + lane] = o;
}

// ---------------------------------------------------------------------------
// LDS-free, barrier-free swapped fp16 MFMA GEMM: scores^T = MFMA(K, Q).
// Depth-4 rotating pipeline (R15-verified optimum): 4 fragment sets R/S/T/U
// in flight; set s consumed at step ks, reloaded for ks+4; no copies,
// counted vmcnt by compiler; setprio around MFMA quartets.
// Epilogue: in-lane {mask,max,argmax,sumexp} -> shfl_xor(32) hi-merge
// (R18-verified) -> cross-wr merge via 2 KB LDS + one barrier -> one
// 128-col chunk partial per qrow per block (NCHUNK=64, part = 4 MB).
// 128(K) x 128(Q) tile, 4 waves (2 wr x 2 wc), acc[2][2] f32x16.
// Grid (64 kTiles, 32 qTiles), block 256.
// ---------------------------------------------------------------------------
#define MFMA_QUARTET(A0, A1, B0, B1)                                            \
    __builtin_amdgcn_s_setprio(1);                                              \
    acc[0][0] = __builtin_amdgcn_mfma_f32_32x32x16_f16(A0, B0, acc[0][0], 0, 0, 0); \
    acc[0][1] = __builtin_amdgcn_mfma_f32_32x32x16_f16(A0, B1, acc[0][1], 0, 0, 0); \
    acc[1][0] = __builtin_amdgcn_mfma_f32_32x32x16_f16(A1, B0, acc[1][0], 0, 0, 0); \
    acc[1][1] = __builtin_amdgcn_mfma_f32_32x32x16_f16(A1, B1, acc[1][1], 0, 0, 0); \
    __builtin_amdgcn_s_setprio(0);

__global__ __launch_bounds__(256)
void scores_mfma(const _Float16* __restrict__ Qp, const _Float16* __restrict__ Kp,
                 const int* __restrict__ ign, float4* __restrict__ part)
{
    __shared__ float4 mrg[2][2][32];      // [wc][j][lx] partials from wr=0

    const int tid = threadIdx.x;          // 0..255
    const int lane = tid & 63;
    const int wave = tid >> 6;            // 0..3
    const int wr = wave >> 1, wc = wave & 1;
    const int hi = lane >> 5, lx = lane & 31;
    const int bx = blockIdx.x;            // K-tile (128 rows), 0..63
    const int by = blockIdx.y;            // Q-tile (128 rows), 0..31

    const f16x8* Kp8 = (const f16x8*)Kp;
    const f16x8* Qp8 = (const f16x8*)Qp;
    const f16x8* A0p = Kp8 + ((size_t)(bx * 4 + wr * 2 + 0) * 32) * 64 + lane;
    const f16x8* A1p = Kp8 + ((size_t)(bx * 4 + wr * 2 + 1) * 32) * 64 + lane;
    const f16x8* B0p = Qp8 + ((size_t)(by * 4 + wc * 2 + 0) * 32) * 64 + lane;
    const f16x8* B1p = Qp8 + ((size_t)(by * 4 + wc * 2 + 1) * 32) * 64 + lane;

    f32x16 acc[2][2];
#pragma unroll
    for (int i = 0; i < 2; ++i)
#pragma unroll
        for (int j = 0; j < 2; ++j) acc[i][j] = (f32x16)0.f;

    // prologue: sets for ks = 0 (R), 1 (S), 2 (T), 3 (U)
    f16x8 rA0 = A0p[0],   rA1 = A1p[0],   rB0 = B0p[0],   rB1 = B1p[0];
    f16x8 sA0 = A0p[64],  sA1 = A1p[64],  sB0 = B0p[64],  sB1 = B1p[64];
    f16x8 tA0 = A0p[128], tA1 = A1p[128], tB0 = B0p[128], tB1 = B1p[128];
    f16x8 uA0 = A0p[192], uA1 = A1p[192], uB0 = B0p[192], uB1 = B1p[192];

    for (int ks = 0; ks < 32; ks += 4) {
        MFMA_QUARTET(rA0, rA1, rB0, rB1)
        if (ks + 4 < 32) {
            const int o = (ks + 4) * 64;
            rA0 = A0p[o]; rA1 = A1p[o]; rB0 = B0p[o]; rB1 = B1p[o];
        }
        MFMA_QUARTET(sA0, sA1, sB0, sB1)
        if (ks + 5 < 32) {
            const int o = (ks + 5) * 64;
            sA0 = A0p[o]; sA1 = A1p[o]; sB0 = B0p[o]; sB1 = B1p[o];
        }
        MFMA_QUARTET(tA0, tA1, tB0, tB1)
        if (ks + 6 < 32) {
            const int o = (ks + 6) * 64;
            tA0 = A0p[o]; tA1 = A1p[o]; tB0 = B0p[o]; tB1 = B1p[o];
        }
        MFMA_QUARTET(uA0, uA1, uB0, uB1)
        if (ks + 7 < 32) {
            const int o = (ks + 7) * 64;
            uA0 = A0p[o]; uA1 = A1p[o]; uB0 = B0p[o]; uB1 = B1p[o];
        }
    }

    // Epilogue:
    //   acc[i][j][r] = score(qrow = by*128 + wc*64 + j*32 + lx,
    //                        kcol = bx*128 + wr*64 + i*32 + (r&3)+8*(r>>2)+4*hi)
    // Step 1 (in-lane + hi-merge, R18-verified): per j -> 64-col partial.
    const int kbase = bx * 128 + wr * 64 + 4 * hi;
    float bmj[2], sej[2]; int bij[2];
#pragma unroll
    for (int j = 0; j < 2; ++j) {
        const int qrow = by * 128 + wc * 64 + j * 32 + lx;
        const int4 ig = ((const int4*)ign)[qrow];   // 4 ignore indices, 16B
        float bm = -INFINITY; int bi = 0x7fffffff;
#pragma unroll
        for (int i = 0; i < 2; ++i) {
#pragma unroll
            for (int r = 0; r < 16; ++r) {
                const int col = kbase + i * 32 + (r & 3) + 8 * (r >> 2);
                float x = acc[i][j][r];
                if (col == ig.x || col == ig.y || col == ig.z || col == ig.w)
                    x = -INFINITY;
                acc[i][j][r] = x;
                if (x > bm || (x == bm && col < bi)) { bm = x; bi = col; }
            }
        }
        float se = 0.f;
#pragma unroll
        for (int i = 0; i < 2; ++i)
#pragma unroll
            for (int r = 0; r < 16; ++r)
                se += __expf(acc[i][j][r] - bm);

        // merge with partner hi-half (same qrow, other 32 k-cols)
        const float obm = __shfl_xor(bm, 32);
        const float ose = __shfl_xor(se, 32);
        const int   obi = __shfl_xor(bi, 32);
        const float nm = fmaxf(bm, obm);
        se = se * __expf(bm - nm) + ose * __expf(obm - nm);
        if (obm > bm || (obm == bm && obi < bi)) bi = obi;
        bm = nm;
        bmj[j] = bm; sej[j] = se; bij[j] = bi;
    }

    // Step 2: cross-wr merge via LDS (wr=0 posts, wr=1 merges+writes).
    if (wr == 0 && hi == 0) {
#pragma unroll
        for (int j = 0; j < 2; ++j)
            mrg[wc][j][lx] = make_float4(bmj[j], sej[j], __int_as_float(bij[j]), 0.f);
    }
    __syncthreads();
    if (wr == 1 && hi == 0) {
#pragma unroll
        for (int j = 0; j < 2; ++j) {
            const float4 o = mrg[wc][j][lx];
            const int   obi = __float_as_int(o.z);
            float bm = bmj[j], se = sej[j]; int bi = bij[j];
            const float nm = fmaxf(bm, o.x);
            se = se * __expf(bm - nm) + o.y * __expf(o.x - nm);
            if (o.x > bm || (o.x == bm && obi < bi)) bi = obi;
            bm = nm;
            const int qrow = by * 128 + wc * 64 + j * 32 + lx;
            part[(size_t)qrow * NCHUNK + bx] =
                make_float4(bm, se, __int_as_float(bi), 0.f);
        }
    }
}

// ---------------------------------------------------------------------------
// Kernel B: 4 rows per 256-thread block (one wave per row).  Merge 64
// chunk partials (one load per lane) -> lse + argmax; positives recomputed
// EXACTLY in fp32 (coalesced row-gather: lane l reads bytes [8l, 8l+8) of
// each row -> one transaction per row).  Fast-math __expf/__logf.
// ---------------------------------------------------------------------------
__global__ __launch_bounds__(256)
void combine_kernel(const float4* __restrict__ part,
                    const float* __restrict__ Q, const float* __restrict__ K,
                    const int* __restrict__ pos,
                    float* __restrict__ logp, float* __restrict__ corrects)
{
    const int row = blockIdx.x * 4 + (threadIdx.x >> 6);
    const int lane = threadIdx.x & 63;

    float4 p0 = part[(size_t)row * NCHUNK + lane];
    float m = p0.x, s = p0.y, av = p0.x;
    int ai = __float_as_int(p0.z);

#pragma unroll
    for (int off = 32; off >= 1; off >>= 1) {
        float om = __shfl_xor(m, off);
        float os = __shfl_xor(s, off);
        float oav = __shfl_xor(av, off);
        int oi = __shfl_xor(ai, off);
        float nm = fmaxf(m, om);
        s = s * __expf(m - nm) + os * __expf(om - nm);
        m = nm;
        if (oav > av || (oav == av && oi < ai)) { av = oav; ai = oi; }
    }
    float lse = m + __logf(s);

    int pi[4];
#pragma unroll
    for (int p = 0; p < 4; ++p) pi[p] = pos[row * P_IDX + p];

    // positive dot-products in exact fp32: lane covers 8 consecutive d-elements
    const float4* q4 = (const float4*)(Q + (size_t)row * D_DIM);
    float4 qa = q4[lane * 2], qb = q4[lane * 2 + 1];
    float d[4];
#pragma unroll
    for (int p = 0; p < 4; ++p) {
        const float4* k4 = (const float4*)(K + (size_t)pi[p] * D_DIM);
        float4 ka = k4[lane * 2], kb = k4[lane * 2 + 1];
        d[p] = qa.x * ka.x + qa.y * ka.y + qa.z * ka.z + qa.w * ka.w
             + qb.x * kb.x + qb.y * kb.y + qb.z * kb.z + qb.w * kb.w;
    }
#pragma unroll
    for (int off = 32; off >= 1; off >>= 1) {
#pragma unroll
        for (int p = 0; p < 4; ++p) d[p] += __shfl_xor(d[p], off);
    }

    if (lane == 0) {
        float ps[4];
#pragma unroll
        for (int p = 0; p < 4; ++p) ps[p] = d[p] * INV_TEMP;
        const bool v1 = (pi[1] != pi[0]);
        const bool v2 = (pi[2] != pi[0]) && (pi[2] != pi[1]);
        const bool v3 = (pi[3] != pi[0]) && (pi[3] != pi[1]) && (pi[3] != pi[2]);
        float pm = ps[0];
        if (v1) pm = fmaxf(pm, ps[1]);
        if (v2) pm = fmaxf(pm, ps[2]);
        if (v3) pm = fmaxf(pm, ps[3]);
        float pse = __expf(ps[0] - pm);
        if (v1) pse += __expf(ps[1] - pm);
        if (v2) pse += __expf(ps[2] - pm);
        if (v3) pse += __expf(ps[3] - pm);
        float pos_lse = pm + __logf(pse);
        logp[row] = pos_lse - lse;
        bool corr = (ai == pi[0]) || (ai == pi[1]) || (ai == pi[2]) || (ai == pi[3]);
        corrects[row] = corr ? 1.0f : 0.0f;
    }
}

// ---------------------------------------------------------------------------
// Kernel C: deterministic fixed-order reduction of logp -> loss
// ---------------------------------------------------------------------------
__global__ __launch_bounds__(256)
void loss_kernel(const float* __restrict__ logp, float* __restrict__ out)
{
    __shared__ float sm[256];
    const int t = threadIdx.x;
    float s = 0.f;
    for (int i = t; i < N_Q; i += 256) s += logp[i];
    sm[t] = s;
    __syncthreads();
    for (int off = 128; off >= 1; off >>= 1) {
        if (t < off) sm[t] += sm[t + off];
        __syncthreads();
    }
    if (t == 0) out[0] = -sm[0];
}

// ---------------------------------------------------------------------------
extern "C" void kernel_launch(void* const* d_in, const int* in_sizes, int n_in,
                              void* d_out, int out_size, void* d_ws, size_t ws_size,
                              hipStream_t stream)
{
    const float* Q = (const float*)d_in[0];
    const float* K = (const float*)d_in[1];
    const int* pos = (const int*)d_in[2];
    const int* ign = (const int*)d_in[3];
    float* out = (float*)d_out;

    // workspace layout (total ~16 MB)
    _Float16* Qp = (_Float16*)d_ws;                              // 4 MB
    _Float16* Kp = Qp + (size_t)N_Q * D_DIM;                     // 8 MB
    float4* part = (float4*)(Kp + (size_t)M_K * D_DIM);          // 4 MB
    float* logp = (float*)(part + (size_t)N_Q * NCHUNK);         // 16 KB

    const int qunits = N_Q / 32 * 32;     // 4096
    const int totunits = qunits + M_K / 32 * 32;   // 12288
    pack_f16<<<totunits / 4, 256, 0, stream>>>(Q, K, Qp, Kp, qunits, totunits);

    dim3 gridA(M_K / 128, N_Q / 128);   // 64 kTiles x 32 qTiles
    scores_mfma<<<gridA, 256, 0, stream>>>(Qp, Kp, ign, part);
    combine_kernel<<<N_Q / 4, 256, 0, stream>>>(part, Q, K, pos, logp, out + 1);
    loss_kernel<<<1, 256, 0, stream>>>(logp, out);
}